// Round 3
// baseline (159.387 us; speedup 1.0000x reference)
//
#include <hip/hip_runtime.h>

// ---------------------------------------------------------------------------
// BatchRelationalModule: b=16, c=64, L=256, F=64
// Factorization: layer0 pre-act = A[b,q,f] + B'[b,p,f]  (B' has bg0 folded in)
// Round 3: occupancy 2->4 blocks/CU; B'-slice staged in LDS (no global loads
// in the steady-state loop); weight fragments loaded with vector dwordx4.
// ---------------------------------------------------------------------------

typedef short s8v __attribute__((ext_vector_type(8)));   // 8 x bf16 (raw bits)
typedef float f4v __attribute__((ext_vector_type(4)));   // MFMA acc / 4 floats

#define LDYB 72   // bf16 per Y1-scratch row (144 B -> b128-aligned, 2-way banks)

__device__ __forceinline__ short bfr(float v) {
  return __builtin_bit_cast(short, (__bf16)v);           // fp32 -> bf16 (RNE)
}
__device__ __forceinline__ unsigned pkbf(float a, float b) {
  unsigned lo = (unsigned short)__builtin_bit_cast(unsigned short, (__bf16)a);
  unsigned hi = (unsigned short)__builtin_bit_cast(unsigned short, (__bf16)b);
  return lo | (hi << 16);
}
__device__ __forceinline__ f4v relu4(f4v v) {
  f4v z = {0.f, 0.f, 0.f, 0.f};
  return __builtin_elementwise_max(v, z);
}
__device__ __forceinline__ s8v cvt8(f4v a, f4v b) {
  s8v r;
  r[0] = bfr(a[0]); r[1] = bfr(a[1]); r[2] = bfr(a[2]); r[3] = bfr(a[3]);
  r[4] = bfr(b[0]); r[5] = bfr(b[1]); r[6] = bfr(b[2]); r[7] = bfr(b[3]);
  return r;
}
__device__ __forceinline__ f4v ldf4(const float* p) {
  return *(const f4v*)p;   // caller guarantees 16B alignment
}

// ---------------------------------------------------------------------------
// Kernel 1: precompute A and B' (fp32), also zero the S accumulator.
// grid: 256 blocks (16 b x 16 l-tiles of 16), 256 threads.
// ---------------------------------------------------------------------------
__global__ __launch_bounds__(256) void k_pre(
    const float* __restrict__ x, const float* __restrict__ Wg0,
    const float* __restrict__ bg0, float* __restrict__ Ag,
    float* __restrict__ Bg, float* __restrict__ Sg) {
  __shared__ float ws[64 * 131];   // Wg0 rows, stride 131
  __shared__ float xs[64 * 17];    // x[ch][l] slice, stride 17

  const int t = threadIdx.x;
  const int b = blockIdx.x >> 4;
  const int l0 = (blockIdx.x & 15) * 16;

  if (blockIdx.x == 0) {           // zero S (d_ws is poisoned 0xAA each launch)
    for (int i = t; i < 16 * 64; i += 256) Sg[i] = 0.f;
  }
  for (int i = t; i < 64 * 130; i += 256) {
    int f = i / 130, d = i - f * 130;
    ws[f * 131 + d] = Wg0[i];
  }
  for (int i = t; i < 64 * 16; i += 256) {
    int ch = i >> 4, li = i & 15;
    xs[ch * 17 + li] = x[b * 16384 + ch * 256 + l0 + li];
  }
  __syncthreads();

  const int f = t & 63;
  const int w = t >> 6;
  float accA[4] = {0.f, 0.f, 0.f, 0.f};
  float accB[4] = {0.f, 0.f, 0.f, 0.f};
  for (int d = 0; d < 64; ++d) {
    float wa = ws[f * 131 + d];
    float wb = ws[f * 131 + 65 + d];
#pragma unroll
    for (int i = 0; i < 4; ++i) {
      float xv = xs[d * 17 + w + 4 * i];
      accA[i] += xv * wa;
      accB[i] += xv * wb;
    }
  }
  const float wca = ws[f * 131 + 64];
  const float wcb = ws[f * 131 + 129];
  const float bias = bg0[f];
#pragma unroll
  for (int i = 0; i < 4; ++i) {
    int l = l0 + w + 4 * i;
    Ag[(b * 256 + l) * 64 + f] = accA[i] + (float)l * wca;
    Bg[(b * 256 + l) * 64 + f] = accB[i] + (float)l * wcb + bias;
  }
}

// ---------------------------------------------------------------------------
// Kernel 2: pair loop. grid (64, 16) x 256 threads -> 4 blocks/CU, 16 waves/CU.
// blockIdx.x: qq = x&3 (q-quarter), pg = x>>2 (16 p per block).
// Block start: stage B'[p0..p0+15] (4 KB) into LDS coalesced; load A rows and
// weight fragments into regs (vector dwordx4). Steady state: NO global loads.
// Per p: B frags via quad-broadcast ds_read_b128 -> X=relu(A+B') in regs ->
// Y1^T = W1*X^T (MFMA, bias in C) -> relu/pack -> 4x ds_write_b64 ->
// 2x ds_read_b128 -> Y2^T = W2*Y1^T -> relu -> vector accumulate.
// LDS = 9216 + 4096 + 256 = 13568 B.
// ---------------------------------------------------------------------------
__global__ __launch_bounds__(256, 4) void k_main(
    const float* __restrict__ Ag, const float* __restrict__ Bg,
    const float* __restrict__ Wg1, const float* __restrict__ bg1,
    const float* __restrict__ Wg2, const float* __restrict__ bg2,
    float* __restrict__ Sg) {
  __shared__ __align__(16) short Ys[4][16 * LDYB];
  __shared__ __align__(16) float Bs[16 * 64];
  __shared__ float Sblk[64];

  const int t = threadIdx.x;
  const int wid = t >> 6;
  const int lane = t & 63;
  const int mm = lane & 15;
  const int quad = lane >> 4;
  const int b = blockIdx.y;
  const int qq = blockIdx.x & 3;
  const int p0 = (blockIdx.x >> 2) * 16;
  const int q0 = (qq * 4 + wid) * 16;

  if (t < 64) Sblk[t] = 0.f;

  // ---- stage B'[16 rows] into LDS: one coalesced dwordx4 per thread ----
  {
    const f4v* Bb4 = (const f4v*)(Bg + (b * 256 + p0) * 64);
    ((f4v*)Bs)[t] = Bb4[t];
  }

  // ---- A rows pinned in registers: A[q0+mm][f = kh*32 + quad*8 + j] ----
  const float* Arow = Ag + (b * 256 + q0 + mm) * 64;
  f4v af0 = ldf4(Arow + quad * 8);
  f4v af1 = ldf4(Arow + quad * 8 + 4);
  f4v af2 = ldf4(Arow + 32 + quad * 8);
  f4v af3 = ldf4(Arow + 36 + quad * 8);

  // ---- weight fragments, A-operand layout: W[gt*16+mm][kh*32+quad*8+j] ----
  s8v W1f[4][2], W2f[4][2];
  f4v c1i[4], c2i[4];
#pragma unroll
  for (int gt = 0; gt < 4; ++gt) {
    c1i[gt] = ldf4(bg1 + gt * 16 + quad * 4);
    c2i[gt] = ldf4(bg2 + gt * 16 + quad * 4);
#pragma unroll
    for (int kh = 0; kh < 2; ++kh) {
      const float* r1 = Wg1 + (gt * 16 + mm) * 64 + kh * 32 + quad * 8;
      const float* r2 = Wg2 + (gt * 16 + mm) * 64 + kh * 32 + quad * 8;
      W1f[gt][kh] = cvt8(ldf4(r1), ldf4(r1 + 4));
      W2f[gt][kh] = cvt8(ldf4(r2), ldf4(r2 + 4));
    }
  }
  __syncthreads();   // Bs staged + Sblk zeroed

  short* Yw = Ys[wid];
  f4v cs[4] = {{0.f,0.f,0.f,0.f},{0.f,0.f,0.f,0.f},
               {0.f,0.f,0.f,0.f},{0.f,0.f,0.f,0.f}};

  for (int ip = 0; ip < 16; ++ip) {
    // ---- B' fragment from LDS (quad-broadcast, conflict-free) ----
    const float* brow = &Bs[ip * 64];
    f4v bq0 = ldf4(brow + quad * 8);
    f4v bq1 = ldf4(brow + quad * 8 + 4);
    f4v bq2 = ldf4(brow + 32 + quad * 8);
    f4v bq3 = ldf4(brow + 36 + quad * 8);

    // ---- X^T fragment: X[q=mm][f] = relu(A+B') ----
    s8v x0 = cvt8(relu4(af0 + bq0), relu4(af1 + bq1));
    s8v x1 = cvt8(relu4(af2 + bq2), relu4(af3 + bq3));

    // ---- layer 1: Y1^T[g][q], bias in C ----
#pragma unroll
    for (int gt = 0; gt < 4; ++gt) {
      f4v a = c1i[gt];
      a = __builtin_amdgcn_mfma_f32_16x16x32_bf16(W1f[gt][0], x0, a, 0, 0, 0);
      a = __builtin_amdgcn_mfma_f32_16x16x32_bf16(W1f[gt][1], x1, a, 0, 0, 0);
      a = relu4(a);
      // lane holds Y1[g = gt*16 + quad*4 + r][q = mm]; store to row q
      unsigned d0 = pkbf(a[0], a[1]);
      unsigned d1 = pkbf(a[2], a[3]);
      *(uint2*)&Yw[mm * LDYB + gt * 16 + quad * 4] = make_uint2(d0, d1);
    }

    // ---- layer 2 B-frag: Y1[q=mm][f = kh*32 + quad*8 + j] ----
    s8v y0 = *(const s8v*)&Yw[mm * LDYB + quad * 8];
    s8v y1 = *(const s8v*)&Yw[mm * LDYB + 32 + quad * 8];

#pragma unroll
    for (int ot = 0; ot < 4; ++ot) {
      f4v a = c2i[ot];
      a = __builtin_amdgcn_mfma_f32_16x16x32_bf16(W2f[ot][0], y0, a, 0, 0, 0);
      a = __builtin_amdgcn_mfma_f32_16x16x32_bf16(W2f[ot][1], y1, a, 0, 0, 0);
      cs[ot] += relu4(a);
    }
  }

  // ---- reduce over q (mm lanes), then block, then global ----
#pragma unroll
  for (int ot = 0; ot < 4; ++ot) {
#pragma unroll
    for (int r = 0; r < 4; ++r) {
      float v = cs[ot][r];
      v += __shfl_xor(v, 1);
      v += __shfl_xor(v, 2);
      v += __shfl_xor(v, 4);
      v += __shfl_xor(v, 8);
      if (mm == 0) atomicAdd(&Sblk[ot * 16 + quad * 4 + r], v);
    }
  }
  __syncthreads();
  if (t < 64) atomicAdd(&Sg[b * 64 + t], Sblk[t]);
}

// ---------------------------------------------------------------------------
// Kernel 3: f-network epilogue. grid 16 x 64 threads.
// ---------------------------------------------------------------------------
__global__ __launch_bounds__(64) void k_final(
    const float* __restrict__ S, const float* __restrict__ Wp,
    const float* __restrict__ bp, const float* __restrict__ Wo,
    const float* __restrict__ bo, float* __restrict__ out) {
  __shared__ float sv[64], tv[64];
  const int b = blockIdx.x, t = threadIdx.x;
  sv[t] = S[b * 64 + t];
  __syncthreads();
  float acc = bp[t];
  for (int g = 0; g < 64; ++g) acc += sv[g] * Wp[t * 64 + g];
  tv[t] = fmaxf(acc, 0.f);
  __syncthreads();
  float o = bo[t];
  for (int f = 0; f < 64; ++f) o += tv[f] * Wo[t * 64 + f];
  out[b * 64 + t] = o;
}

// ---------------------------------------------------------------------------
extern "C" void kernel_launch(void* const* d_in, const int* in_sizes, int n_in,
                              void* d_out, int out_size, void* d_ws, size_t ws_size,
                              hipStream_t stream) {
  const float* x   = (const float*)d_in[0];
  const float* Wg0 = (const float*)d_in[1];
  const float* bg0 = (const float*)d_in[2];
  const float* Wg1 = (const float*)d_in[3];
  const float* bg1 = (const float*)d_in[4];
  const float* Wg2 = (const float*)d_in[5];
  const float* bg2 = (const float*)d_in[6];
  const float* Wp  = (const float*)d_in[7];
  const float* bp  = (const float*)d_in[8];
  const float* Wo  = (const float*)d_in[9];
  const float* bo  = (const float*)d_in[10];
  float* out = (float*)d_out;

  float* Ag = (float*)d_ws;            // [16][256][64] fp32 = 1 MB
  float* Bg = Ag + 16 * 256 * 64;      // [16][256][64] fp32 = 1 MB
  float* Sg = Bg + 16 * 256 * 64;      // [16][64] fp32 accumulator

  k_pre<<<256, 256, 0, stream>>>(x, Wg0, bg0, Ag, Bg, Sg);
  k_main<<<dim3(64, 16), 256, 0, stream>>>(Ag, Bg, Wg1, bg1, Wg2, bg2, Sg);
  k_final<<<16, 64, 0, stream>>>(Sg, Wp, bp, Wo, bo, out);
}

// Round 5
// 114.434 us; speedup vs baseline: 1.3928x; 1.3928x over previous
//
#include <hip/hip_runtime.h>

// ---------------------------------------------------------------------------
// BatchRelationalModule: b=16, c=64, L=256, F=64
// Factorization: layer0 pre-act = A[b,q,f] + B'[b,p,f]  (B' has bg0 folded in)
// Round 5 (= round 4 with the correct builtin name):
//  * asm register-barrier (KEEP) pins weight/bias/A fragments in VGPRs --
//    rounds 2/3 showed the compiler sinking these loads into the loop
//    (VGPR_Count 64..88, 35 MB FETCH, 3200 cyc/iter).
//  * layer-2 via v_mfma_f32_16x16x16_bf16 (__builtin_amdgcn_mfma_f32_16x16x16bf16_1k):
//    layer-1's C/D fragment (row=quad*4+r, col=mm) is bit-identical to the
//    K=16 B-operand fragment (k=quad*4+i, n=mm) -> NO LDS round-trip between
//    layers at all.
// ---------------------------------------------------------------------------

typedef short s8v __attribute__((ext_vector_type(8)));   // 8 x bf16 (4 VGPR)
typedef short s4v __attribute__((ext_vector_type(4)));   // 4 x bf16 (2 VGPR)
typedef float f4v __attribute__((ext_vector_type(4)));   // 4 x f32  (4 VGPR)

#define KEEP(x) asm volatile("" : "+v"(x))   // opaque: forbids remat/sink

#define MFMA16(a, b, c) __builtin_amdgcn_mfma_f32_16x16x16bf16_1k(a, b, c, 0, 0, 0)

__device__ __forceinline__ short bfr(float v) {
  return __builtin_bit_cast(short, (__bf16)v);           // fp32 -> bf16 (RNE)
}
__device__ __forceinline__ f4v relu4(f4v v) {
  f4v z = {0.f, 0.f, 0.f, 0.f};
  return __builtin_elementwise_max(v, z);
}
__device__ __forceinline__ s8v cvt8(f4v a, f4v b) {
  s8v r;
  r[0] = bfr(a[0]); r[1] = bfr(a[1]); r[2] = bfr(a[2]); r[3] = bfr(a[3]);
  r[4] = bfr(b[0]); r[5] = bfr(b[1]); r[6] = bfr(b[2]); r[7] = bfr(b[3]);
  return r;
}
__device__ __forceinline__ s4v cvt4(f4v a) {
  s4v r;
  r[0] = bfr(a[0]); r[1] = bfr(a[1]); r[2] = bfr(a[2]); r[3] = bfr(a[3]);
  return r;
}
__device__ __forceinline__ f4v ldf4(const float* p) {
  return *(const f4v*)p;
}

// ---------------------------------------------------------------------------
// Kernel 1: precompute A and B' (fp32), also zero the S accumulator.
// ---------------------------------------------------------------------------
__global__ __launch_bounds__(256) void k_pre(
    const float* __restrict__ x, const float* __restrict__ Wg0,
    const float* __restrict__ bg0, float* __restrict__ Ag,
    float* __restrict__ Bg, float* __restrict__ Sg) {
  __shared__ float ws[64 * 131];
  __shared__ float xs[64 * 17];

  const int t = threadIdx.x;
  const int b = blockIdx.x >> 4;
  const int l0 = (blockIdx.x & 15) * 16;

  if (blockIdx.x == 0) {
    for (int i = t; i < 16 * 64; i += 256) Sg[i] = 0.f;
  }
  for (int i = t; i < 64 * 130; i += 256) {
    int f = i / 130, d = i - f * 130;
    ws[f * 131 + d] = Wg0[i];
  }
  for (int i = t; i < 64 * 16; i += 256) {
    int ch = i >> 4, li = i & 15;
    xs[ch * 17 + li] = x[b * 16384 + ch * 256 + l0 + li];
  }
  __syncthreads();

  const int f = t & 63;
  const int w = t >> 6;
  float accA[4] = {0.f, 0.f, 0.f, 0.f};
  float accB[4] = {0.f, 0.f, 0.f, 0.f};
  for (int d = 0; d < 64; ++d) {
    float wa = ws[f * 131 + d];
    float wb = ws[f * 131 + 65 + d];
#pragma unroll
    for (int i = 0; i < 4; ++i) {
      float xv = xs[d * 17 + w + 4 * i];
      accA[i] += xv * wa;
      accB[i] += xv * wb;
    }
  }
  const float wca = ws[f * 131 + 64];
  const float wcb = ws[f * 131 + 129];
  const float bias = bg0[f];
#pragma unroll
  for (int i = 0; i < 4; ++i) {
    int l = l0 + w + 4 * i;
    Ag[(b * 256 + l) * 64 + f] = accA[i] + (float)l * wca;
    Bg[(b * 256 + l) * 64 + f] = accB[i] + (float)l * wcb + bias;
  }
}

// ---------------------------------------------------------------------------
// Kernel 2: pair loop. grid (32, 16) x 256 thr, 2 blocks/CU, all resident.
// Per p: B'-frag (LDS broadcast, prefetched) -> X=relu(A+B') ->
// layer1 = 2x mfma 16x16x32 (bias in C) -> relu/pack (s4v) ->
// layer2 = 4x mfma 16x16x16 per output tile, DIRECT chaining (no LDS) ->
// relu -> accumulate. Weights/A/biases pinned in VGPRs via KEEP.
// ---------------------------------------------------------------------------
__global__ __launch_bounds__(256, 2) void k_main(
    const float* __restrict__ Ag, const float* __restrict__ Bg,
    const float* __restrict__ Wg1, const float* __restrict__ bg1,
    const float* __restrict__ Wg2, const float* __restrict__ bg2,
    float* __restrict__ Sg) {
  __shared__ __align__(16) float Bs[32 * 64];   // 8 KB
  __shared__ float Sblk[64];

  const int t = threadIdx.x;
  const int wid = t >> 6;
  const int lane = t & 63;
  const int mm = lane & 15;
  const int quad = lane >> 4;
  const int b = blockIdx.y;
  const int qq = blockIdx.x & 3;
  const int p0 = (blockIdx.x >> 2) * 32;
  const int q0 = (qq * 4 + wid) * 16;

  if (t < 64) Sblk[t] = 0.f;

  // ---- stage B'[32 rows] (8 KB) into LDS, coalesced dwordx4 ----
  {
    const f4v* Bb4 = (const f4v*)(Bg + (b * 256 + p0) * 64);
    ((f4v*)Bs)[t] = Bb4[t];
    ((f4v*)Bs)[t + 256] = Bb4[t + 256];
  }

  // ---- A rows pinned: A[q0+mm][f = kh*32 + quad*8 + j] ----
  const float* Arow = Ag + (b * 256 + q0 + mm) * 64;
  f4v af0 = ldf4(Arow + quad * 8);
  f4v af1 = ldf4(Arow + quad * 8 + 4);
  f4v af2 = ldf4(Arow + 32 + quad * 8);
  f4v af3 = ldf4(Arow + 36 + quad * 8);

  // ---- layer-1 weights, K32 A-operand: W1[gt*16+mm][kh*32+quad*8+j] ----
  s8v W1f[4][2];
  // ---- layer-2 weights, K16 A-operand: W2[ot*16+mm][gt*16+quad*4+i] ----
  s4v W2f[4][4];
  f4v c1i[4], c2i[4];
#pragma unroll
  for (int gt = 0; gt < 4; ++gt) {
    c1i[gt] = ldf4(bg1 + gt * 16 + quad * 4);
    c2i[gt] = ldf4(bg2 + gt * 16 + quad * 4);
#pragma unroll
    for (int kh = 0; kh < 2; ++kh) {
      const float* r1 = Wg1 + (gt * 16 + mm) * 64 + kh * 32 + quad * 8;
      W1f[gt][kh] = cvt8(ldf4(r1), ldf4(r1 + 4));
    }
#pragma unroll
    for (int kt = 0; kt < 4; ++kt) {
      const float* r2 = Wg2 + (gt * 16 + mm) * 64 + kt * 16 + quad * 4;
      W2f[gt][kt] = cvt4(ldf4(r2));
    }
  }
  // Pin everything loop-invariant in registers (defeat remat/sink).
#pragma unroll
  for (int gt = 0; gt < 4; ++gt) {
    KEEP(W1f[gt][0]); KEEP(W1f[gt][1]);
    KEEP(W2f[gt][0]); KEEP(W2f[gt][1]); KEEP(W2f[gt][2]); KEEP(W2f[gt][3]);
    KEEP(c1i[gt]); KEEP(c2i[gt]);
  }
  KEEP(af0); KEEP(af1); KEEP(af2); KEEP(af3);

  __syncthreads();   // Bs staged + Sblk zeroed

  f4v cs[4] = {{0.f,0.f,0.f,0.f},{0.f,0.f,0.f,0.f},
               {0.f,0.f,0.f,0.f},{0.f,0.f,0.f,0.f}};

  // prefetch B'-frag for p = p0 (quad-broadcast ds_read_b128)
  f4v bq0 = ldf4(Bs + quad * 8);
  f4v bq1 = ldf4(Bs + quad * 8 + 4);
  f4v bq2 = ldf4(Bs + 32 + quad * 8);
  f4v bq3 = ldf4(Bs + 36 + quad * 8);

  for (int ip = 0; ip < 32; ++ip) {
    const float* bn = Bs + ((ip < 31) ? ip + 1 : 31) * 64;
    f4v bn0 = ldf4(bn + quad * 8);
    f4v bn1 = ldf4(bn + quad * 8 + 4);
    f4v bn2 = ldf4(bn + 32 + quad * 8);
    f4v bn3 = ldf4(bn + 36 + quad * 8);

    // ---- X fragment: X[q=mm][f] = relu(A+B'), K32 A/B-operand layout ----
    s8v x0 = cvt8(relu4(af0 + bq0), relu4(af1 + bq1));
    s8v x1 = cvt8(relu4(af2 + bq2), relu4(af3 + bq3));

    // ---- layer 1 + direct layer 2 (no LDS between) ----
    s4v pk[4];
#pragma unroll
    for (int gt = 0; gt < 4; ++gt) {
      f4v a = c1i[gt];
      a = __builtin_amdgcn_mfma_f32_16x16x32_bf16(W1f[gt][0], x0, a, 0, 0, 0);
      a = __builtin_amdgcn_mfma_f32_16x16x32_bf16(W1f[gt][1], x1, a, 0, 0, 0);
      // lane now holds Y1[g=gt*16+quad*4+r][q=mm] -- exactly the K16
      // B-operand fragment (k=quad*4+i, n=mm) after relu+pack:
      pk[gt] = cvt4(relu4(a));
    }
#pragma unroll
    for (int ot = 0; ot < 4; ++ot) {
      f4v a = c2i[ot];
      a = MFMA16(W2f[ot][0], pk[0], a);
      a = MFMA16(W2f[ot][1], pk[1], a);
      a = MFMA16(W2f[ot][2], pk[2], a);
      a = MFMA16(W2f[ot][3], pk[3], a);
      cs[ot] += relu4(a);    // lane: o = ot*16+quad*4+r, q = mm
    }

    bq0 = bn0; bq1 = bn1; bq2 = bn2; bq3 = bn3;
  }

  // ---- reduce over q (mm lanes) -> Sblk[o] -> global ----
#pragma unroll
  for (int ot = 0; ot < 4; ++ot) {
#pragma unroll
    for (int r = 0; r < 4; ++r) {
      float v = cs[ot][r];
      v += __shfl_xor(v, 1);
      v += __shfl_xor(v, 2);
      v += __shfl_xor(v, 4);
      v += __shfl_xor(v, 8);
      if (mm == 0) atomicAdd(&Sblk[ot * 16 + quad * 4 + r], v);
    }
  }
  __syncthreads();
  if (t < 64) atomicAdd(&Sg[b * 64 + t], Sblk[t]);
}

// ---------------------------------------------------------------------------
// Kernel 3: f-network epilogue. grid 16 x 64 threads.
// ---------------------------------------------------------------------------
__global__ __launch_bounds__(64) void k_final(
    const float* __restrict__ S, const float* __restrict__ Wp,
    const float* __restrict__ bp, const float* __restrict__ Wo,
    const float* __restrict__ bo, float* __restrict__ out) {
  __shared__ float sv[64], tv[64];
  const int b = blockIdx.x, t = threadIdx.x;
  sv[t] = S[b * 64 + t];
  __syncthreads();
  float acc = bp[t];
  for (int g = 0; g < 64; ++g) acc += sv[g] * Wp[t * 64 + g];
  tv[t] = fmaxf(acc, 0.f);
  __syncthreads();
  float o = bo[t];
  for (int f = 0; f < 64; ++f) o += tv[f] * Wo[t * 64 + f];
  out[b * 64 + t] = o;
}

// ---------------------------------------------------------------------------
extern "C" void kernel_launch(void* const* d_in, const int* in_sizes, int n_in,
                              void* d_out, int out_size, void* d_ws, size_t ws_size,
                              hipStream_t stream) {
  const float* x   = (const float*)d_in[0];
  const float* Wg0 = (const float*)d_in[1];
  const float* bg0 = (const float*)d_in[2];
  const float* Wg1 = (const float*)d_in[3];
  const float* bg1 = (const float*)d_in[4];
  const float* Wg2 = (const float*)d_in[5];
  const float* bg2 = (const float*)d_in[6];
  const float* Wp  = (const float*)d_in[7];
  const float* bp  = (const float*)d_in[8];
  const float* Wo  = (const float*)d_in[9];
  const float* bo  = (const float*)d_in[10];
  float* out = (float*)d_out;

  float* Ag = (float*)d_ws;            // [16][256][64] fp32 = 1 MB
  float* Bg = Ag + 16 * 256 * 64;      // [16][256][64] fp32 = 1 MB
  float* Sg = Bg + 16 * 256 * 64;      // [16][64] fp32 accumulator

  k_pre<<<256, 256, 0, stream>>>(x, Wg0, bg0, Ag, Bg, Sg);
  k_main<<<dim3(32, 16), 256, 0, stream>>>(Ag, Bg, Wg1, bg1, Wg2, bg2, Sg);
  k_final<<<16, 64, 0, stream>>>(Sg, Wp, bp, Wo, bo, out);
}

// Round 6
// 113.254 us; speedup vs baseline: 1.4073x; 1.0104x over previous
//
#include <hip/hip_runtime.h>

// ---------------------------------------------------------------------------
// BatchRelationalModule: b=16, c=64, L=256, F=64
// Factorization: layer0 pre-act = A[b,q,f] + B'[b,p,f]  (B' has bg0 folded in)
// Round 6: KILL THE GLOBAL ATOMICS. Rounds 1/2/5 all pinned at ~41 us and
// round 3 (2x blocks) at exactly 2x: cost ~ 82 ns/block, independent of the
// inner loop => the 64 atomicAdd/block into one 4 KB region serialized at
// ~190 cyc/line-RMW (512 per cache line = 97 K cyc = 40 us). Replace with
// per-block partial stores (no contention) + reduction in k_final.
// ---------------------------------------------------------------------------

typedef short s8v __attribute__((ext_vector_type(8)));   // 8 x bf16 (4 VGPR)
typedef short s4v __attribute__((ext_vector_type(4)));   // 4 x bf16 (2 VGPR)
typedef float f4v __attribute__((ext_vector_type(4)));   // 4 x f32  (4 VGPR)

#define KEEP(x) asm volatile("" : "+v"(x))   // opaque: forbids remat/sink

#define MFMA16(a, b, c) __builtin_amdgcn_mfma_f32_16x16x16bf16_1k(a, b, c, 0, 0, 0)

__device__ __forceinline__ short bfr(float v) {
  return __builtin_bit_cast(short, (__bf16)v);           // fp32 -> bf16 (RNE)
}
__device__ __forceinline__ f4v relu4(f4v v) {
  f4v z = {0.f, 0.f, 0.f, 0.f};
  return __builtin_elementwise_max(v, z);
}
__device__ __forceinline__ s8v cvt8(f4v a, f4v b) {
  s8v r;
  r[0] = bfr(a[0]); r[1] = bfr(a[1]); r[2] = bfr(a[2]); r[3] = bfr(a[3]);
  r[4] = bfr(b[0]); r[5] = bfr(b[1]); r[6] = bfr(b[2]); r[7] = bfr(b[3]);
  return r;
}
__device__ __forceinline__ s4v cvt4(f4v a) {
  s4v r;
  r[0] = bfr(a[0]); r[1] = bfr(a[1]); r[2] = bfr(a[2]); r[3] = bfr(a[3]);
  return r;
}
__device__ __forceinline__ f4v ldf4(const float* p) {
  return *(const f4v*)p;
}

// ---------------------------------------------------------------------------
// Kernel 1: precompute A and B' (fp32).
// ---------------------------------------------------------------------------
__global__ __launch_bounds__(256) void k_pre(
    const float* __restrict__ x, const float* __restrict__ Wg0,
    const float* __restrict__ bg0, float* __restrict__ Ag,
    float* __restrict__ Bg) {
  __shared__ float ws[64 * 131];
  __shared__ float xs[64 * 17];

  const int t = threadIdx.x;
  const int b = blockIdx.x >> 4;
  const int l0 = (blockIdx.x & 15) * 16;

  for (int i = t; i < 64 * 130; i += 256) {
    int f = i / 130, d = i - f * 130;
    ws[f * 131 + d] = Wg0[i];
  }
  for (int i = t; i < 64 * 16; i += 256) {
    int ch = i >> 4, li = i & 15;
    xs[ch * 17 + li] = x[b * 16384 + ch * 256 + l0 + li];
  }
  __syncthreads();

  const int f = t & 63;
  const int w = t >> 6;
  float accA[4] = {0.f, 0.f, 0.f, 0.f};
  float accB[4] = {0.f, 0.f, 0.f, 0.f};
  for (int d = 0; d < 64; ++d) {
    float wa = ws[f * 131 + d];
    float wb = ws[f * 131 + 65 + d];
#pragma unroll
    for (int i = 0; i < 4; ++i) {
      float xv = xs[d * 17 + w + 4 * i];
      accA[i] += xv * wa;
      accB[i] += xv * wb;
    }
  }
  const float wca = ws[f * 131 + 64];
  const float wcb = ws[f * 131 + 129];
  const float bias = bg0[f];
#pragma unroll
  for (int i = 0; i < 4; ++i) {
    int l = l0 + w + 4 * i;
    Ag[(b * 256 + l) * 64 + f] = accA[i] + (float)l * wca;
    Bg[(b * 256 + l) * 64 + f] = accB[i] + (float)l * wcb + bias;
  }
}

// ---------------------------------------------------------------------------
// Kernel 2: pair loop. grid (32, 16) x 256 thr, 2 blocks/CU.
// Per p: B'-frag (LDS broadcast) -> X=relu(A+B') -> layer1 = 2x mfma16x16x32
// (bias in C) -> relu/pack -> layer2 = 4x mfma16x16x16 direct chaining ->
// relu -> accumulate. Epilogue: block partial -> DISTINCT global slot
// (coalesced store, NO atomics).
// ---------------------------------------------------------------------------
__global__ __launch_bounds__(256, 2) void k_main(
    const float* __restrict__ Ag, const float* __restrict__ Bg,
    const float* __restrict__ Wg1, const float* __restrict__ bg1,
    const float* __restrict__ Wg2, const float* __restrict__ bg2,
    float* __restrict__ Part) {
  __shared__ __align__(16) float Bs[32 * 64];   // 8 KB
  __shared__ float Sblk[64];

  const int t = threadIdx.x;
  const int wid = t >> 6;
  const int lane = t & 63;
  const int mm = lane & 15;
  const int quad = lane >> 4;
  const int b = blockIdx.y;
  const int blkx = blockIdx.x;          // 0..31
  const int qq = blkx & 3;
  const int p0 = (blkx >> 2) * 32;
  const int q0 = (qq * 4 + wid) * 16;

  if (t < 64) Sblk[t] = 0.f;

  // ---- stage B'[32 rows] (8 KB) into LDS, coalesced dwordx4 ----
  {
    const f4v* Bb4 = (const f4v*)(Bg + (b * 256 + p0) * 64);
    ((f4v*)Bs)[t] = Bb4[t];
    ((f4v*)Bs)[t + 256] = Bb4[t + 256];
  }

  // ---- A rows pinned: A[q0+mm][f = kh*32 + quad*8 + j] ----
  const float* Arow = Ag + (b * 256 + q0 + mm) * 64;
  f4v af0 = ldf4(Arow + quad * 8);
  f4v af1 = ldf4(Arow + quad * 8 + 4);
  f4v af2 = ldf4(Arow + 32 + quad * 8);
  f4v af3 = ldf4(Arow + 36 + quad * 8);

  // ---- layer-1 weights, K32 A-operand: W1[gt*16+mm][kh*32+quad*8+j] ----
  s8v W1f[4][2];
  // ---- layer-2 weights, K16 A-operand: W2[ot*16+mm][gt*16+quad*4+i] ----
  s4v W2f[4][4];
  f4v c1i[4], c2i[4];
#pragma unroll
  for (int gt = 0; gt < 4; ++gt) {
    c1i[gt] = ldf4(bg1 + gt * 16 + quad * 4);
    c2i[gt] = ldf4(bg2 + gt * 16 + quad * 4);
#pragma unroll
    for (int kh = 0; kh < 2; ++kh) {
      const float* r1 = Wg1 + (gt * 16 + mm) * 64 + kh * 32 + quad * 8;
      W1f[gt][kh] = cvt8(ldf4(r1), ldf4(r1 + 4));
    }
#pragma unroll
    for (int kt = 0; kt < 4; ++kt) {
      const float* r2 = Wg2 + (gt * 16 + mm) * 64 + kt * 16 + quad * 4;
      W2f[gt][kt] = cvt4(ldf4(r2));
    }
  }
  // Pin loop-invariants in registers (defeat remat/sink).
#pragma unroll
  for (int gt = 0; gt < 4; ++gt) {
    KEEP(W1f[gt][0]); KEEP(W1f[gt][1]);
    KEEP(W2f[gt][0]); KEEP(W2f[gt][1]); KEEP(W2f[gt][2]); KEEP(W2f[gt][3]);
    KEEP(c1i[gt]); KEEP(c2i[gt]);
  }
  KEEP(af0); KEEP(af1); KEEP(af2); KEEP(af3);

  __syncthreads();   // Bs staged + Sblk zeroed

  f4v cs[4] = {{0.f,0.f,0.f,0.f},{0.f,0.f,0.f,0.f},
               {0.f,0.f,0.f,0.f},{0.f,0.f,0.f,0.f}};

  // prefetch B'-frag for p = p0 (quad-broadcast ds_read_b128)
  f4v bq0 = ldf4(Bs + quad * 8);
  f4v bq1 = ldf4(Bs + quad * 8 + 4);
  f4v bq2 = ldf4(Bs + 32 + quad * 8);
  f4v bq3 = ldf4(Bs + 36 + quad * 8);

  for (int ip = 0; ip < 32; ++ip) {
    const float* bn = Bs + ((ip < 31) ? ip + 1 : 31) * 64;
    f4v bn0 = ldf4(bn + quad * 8);
    f4v bn1 = ldf4(bn + quad * 8 + 4);
    f4v bn2 = ldf4(bn + 32 + quad * 8);
    f4v bn3 = ldf4(bn + 36 + quad * 8);

    // ---- X fragment: X[q=mm][f] = relu(A+B'), K32 A/B-operand layout ----
    s8v x0 = cvt8(relu4(af0 + bq0), relu4(af1 + bq1));
    s8v x1 = cvt8(relu4(af2 + bq2), relu4(af3 + bq3));

    // ---- layer 1 + direct layer 2 (no LDS between) ----
    s4v pk[4];
#pragma unroll
    for (int gt = 0; gt < 4; ++gt) {
      f4v a = c1i[gt];
      a = __builtin_amdgcn_mfma_f32_16x16x32_bf16(W1f[gt][0], x0, a, 0, 0, 0);
      a = __builtin_amdgcn_mfma_f32_16x16x32_bf16(W1f[gt][1], x1, a, 0, 0, 0);
      // lane: Y1[g=gt*16+quad*4+r][q=mm] == K16 B-operand frag (k=quad*4+i, n=mm)
      pk[gt] = cvt4(relu4(a));
    }
#pragma unroll
    for (int ot = 0; ot < 4; ++ot) {
      f4v a = c2i[ot];
      a = MFMA16(W2f[ot][0], pk[0], a);
      a = MFMA16(W2f[ot][1], pk[1], a);
      a = MFMA16(W2f[ot][2], pk[2], a);
      a = MFMA16(W2f[ot][3], pk[3], a);
      cs[ot] += relu4(a);    // lane: o = ot*16+quad*4+r, q = mm
    }

    bq0 = bn0; bq1 = bn1; bq2 = bn2; bq3 = bn3;
  }

  // ---- reduce over q (mm lanes) -> Sblk (LDS) -> distinct global slot ----
#pragma unroll
  for (int ot = 0; ot < 4; ++ot) {
#pragma unroll
    for (int r = 0; r < 4; ++r) {
      float v = cs[ot][r];
      v += __shfl_xor(v, 1);
      v += __shfl_xor(v, 2);
      v += __shfl_xor(v, 4);
      v += __shfl_xor(v, 8);
      if (mm == 0) atomicAdd(&Sblk[ot * 16 + quad * 4 + r], v);  // LDS only
    }
  }
  __syncthreads();
  if (t < 64) Part[(b * 32 + blkx) * 64 + t] = Sblk[t];   // no contention
}

// ---------------------------------------------------------------------------
// Kernel 3: reduce 32 partials per (b,o), then f-network. grid 16 x 64.
// ---------------------------------------------------------------------------
__global__ __launch_bounds__(64) void k_final(
    const float* __restrict__ Part, const float* __restrict__ Wp,
    const float* __restrict__ bp, const float* __restrict__ Wo,
    const float* __restrict__ bo, float* __restrict__ out) {
  __shared__ float sv[64], tv[64];
  const int b = blockIdx.x, t = threadIdx.x;
  float s = 0.f;
  const float* Pb = Part + b * 32 * 64;
#pragma unroll
  for (int j = 0; j < 32; ++j) s += Pb[j * 64 + t];   // coalesced rows
  sv[t] = s;
  __syncthreads();
  float acc = bp[t];
  for (int g = 0; g < 64; ++g) acc += sv[g] * Wp[t * 64 + g];
  tv[t] = fmaxf(acc, 0.f);
  __syncthreads();
  float o = bo[t];
  for (int f = 0; f < 64; ++f) o += tv[f] * Wo[t * 64 + f];
  out[b * 64 + t] = o;
}

// ---------------------------------------------------------------------------
extern "C" void kernel_launch(void* const* d_in, const int* in_sizes, int n_in,
                              void* d_out, int out_size, void* d_ws, size_t ws_size,
                              hipStream_t stream) {
  const float* x   = (const float*)d_in[0];
  const float* Wg0 = (const float*)d_in[1];
  const float* bg0 = (const float*)d_in[2];
  const float* Wg1 = (const float*)d_in[3];
  const float* bg1 = (const float*)d_in[4];
  const float* Wg2 = (const float*)d_in[5];
  const float* bg2 = (const float*)d_in[6];
  const float* Wp  = (const float*)d_in[7];
  const float* bp  = (const float*)d_in[8];
  const float* Wo  = (const float*)d_in[9];
  const float* bo  = (const float*)d_in[10];
  float* out = (float*)d_out;

  float* Ag   = (float*)d_ws;            // [16][256][64] fp32 = 1 MB
  float* Bg   = Ag + 16 * 256 * 64;      // [16][256][64] fp32 = 1 MB
  float* Part = Bg + 16 * 256 * 64;      // [16][32][64] fp32 = 128 KB

  k_pre<<<256, 256, 0, stream>>>(x, Wg0, bg0, Ag, Bg);
  k_main<<<dim3(32, 16), 256, 0, stream>>>(Ag, Bg, Wg1, bg1, Wg2, bg2, Part);
  k_final<<<16, 64, 0, stream>>>(Part, Wp, bp, Wo, bo, out);
}